// Round 16
// baseline (954.430 us; speedup 1.0000x reference)
//
#include <hip/hip_runtime.h>
#include <hip/hip_bf16.h>

// LSTMReg on MI355X — round 16: MERGED GATES, ONE BARRIER PER STEP (fp16).
// r15 audit: iter 1740 cyc = 620 MFMA + ~250 gates + ~900 sync tax (2
// barriers + exposed latency, phase-locked waves). Merge: each wave owns one
// 16-row tile PER GATE ({64g+16w+col}) so its 4 accs hold z_i,f,g,o for the
// same 4 features of its chain-col -> gates fully in-lane, zp deleted, ONE
// barrier/iter. 8 waves (wv0-3 L0 step t, wv4-7 L1 step t-1), 64 blocks.
// vs r11 (which failed here): fp16 halves weights (64 VGPR) and MFMAs (16),
// no parity-DPP; launch_bounds(512,2) -> 256-VGPR budget, no spill.

typedef _Float16 f16x8 __attribute__((ext_vector_type(8)));
typedef _Float16 f16x4 __attribute__((ext_vector_type(4)));
typedef float f32x4  __attribute__((ext_vector_type(4)));

#define MFMAH(A, B, C) __builtin_amdgcn_mfma_f32_16x16x32_f16(A, B, C, 0, 0, 0)

constexpr int T_LEN = 1024;
constexpr int H     = 64;
constexpr int NCH   = 8;     // chains per block (MFMA cols 0-7; 8-15 mirror)
constexpr int NTHR  = 512;   // 8 waves
constexpr int NBLK  = 64;    // 512 chains / 8

// x fragment buffer: [blk][t][kt(2)][lq(4)][ch(8)][8 halfs]  (as r15)
constexpr int    XT_HALFS   = 2 * 4 * 8 * 8;                // 512 halfs per t
constexpr size_t XBLK_HALFS = (size_t)T_LEN * XT_HALFS;     // 1 MiB per block

__device__ __forceinline__ float sigm_f(float x) {
  return __builtin_amdgcn_rcpf(1.0f + __expf(-x));
}
__device__ __forceinline__ float tanh_f(float x) {
  return 1.0f - 2.0f * __builtin_amdgcn_rcpf(1.0f + __expf(2.0f * x));
}

// ---- pre-pass: x [512][1024][64] fp32 -> fp16 fragment packets (= r15) ----
__global__ __launch_bounds__(256, 4) void xconv(const float* __restrict__ x,
                                                _Float16* __restrict__ xf) {
  const int gid = blockIdx.x * 256 + threadIdx.x;  // (chain, t, lq)
  const int lq    = gid & 3;
  const int t     = (gid >> 2) & (T_LEN - 1);
  const int chain = gid >> 12;                     // 0..511
  const int ch  = chain & 7;
  const int blk = chain >> 3;
  const float* src = x + ((size_t)chain * T_LEN + t) * H + 8 * lq;
  float4 v0 = *reinterpret_cast<const float4*>(src);
  float4 v1 = *reinterpret_cast<const float4*>(src + 4);
  float4 v2 = *reinterpret_cast<const float4*>(src + 32);
  float4 v3 = *reinterpret_cast<const float4*>(src + 36);
  float a[8]  = {v0.x, v0.y, v0.z, v0.w, v1.x, v1.y, v1.z, v1.w};
  float c8[8] = {v2.x, v2.y, v2.z, v2.w, v3.x, v3.y, v3.z, v3.w};
  f16x8 p0, p1;
#pragma unroll
  for (int e = 0; e < 8; ++e) {
    p0[e] = (_Float16)a[e];
    p1[e] = (_Float16)c8[e];
  }
  _Float16* dst = xf + (size_t)blk * XBLK_HALFS + (size_t)t * XT_HALFS +
                  lq * 64 + ch * 8;
  *reinterpret_cast<f16x8*>(dst)       = p0;  // kt0 (feats 0-31)
  *reinterpret_cast<f16x8*>(dst + 256) = p1;  // kt1 (feats 32-63)
}

__global__ __launch_bounds__(NTHR, 2) void lstm_fused(
    const _Float16* __restrict__ xf,
    const float* __restrict__ w_ih0, const float* __restrict__ w_hh0,
    const float* __restrict__ b_ih0, const float* __restrict__ b_hh0,
    const float* __restrict__ w_ih1, const float* __restrict__ w_hh1,
    const float* __restrict__ b_ih1, const float* __restrict__ b_hh1,
    const float* __restrict__ fc_w, const float* __restrict__ fc_b,
    float* __restrict__ out) {
  const int tid = threadIdx.x;
  const int wv  = tid >> 6;
  const int L   = wv >> 2;   // 0: layer0 waves (wv0-3), 1: layer1 (wv4-7)
  const int w   = wv & 3;    // feature slice: feats 16w..16w+15 (all 4 gates)
  const int l   = tid & 63;
  const int col = l & 15;    // MFMA column = chain (0-7 real, 8-15 mirror)
  const int lq  = l >> 4;
  const int blk = blockIdx.x;

  // h buffers: [layer][buf][kt(2)][lq(4)][ch(8)][e(8)] halfs = 1 KiB each
  __shared__ __align__(16) _Float16 hb[2][2][512];
  __shared__ float fcw_s[H];
  __shared__ float hfin[NCH][H];

  for (int i = tid; i < 2 * 2 * 512; i += NTHR) ((_Float16*)hb)[i] = (_Float16)0.f;
  if (tid < H) fcw_s[tid] = fc_w[tid];

  // ---- weights: gate g tile = rows 64g + 16w + col; k0 = 32kt + 8lq ----
  const float* wih = L ? w_ih1 : w_ih0;
  const float* whh = L ? w_hh1 : w_hh0;
  const float* bih = L ? b_ih1 : b_ih0;
  const float* bhh = L ? b_hh1 : b_hh0;
  f16x8 w16[4][4];  // [gate][kt] = 64 VGPR
  f32x4 biasf[4];   // [gate], per-lane rows 16w + 4lq + r
#pragma unroll
  for (int g = 0; g < 4; ++g) {
#pragma unroll
    for (int kt = 0; kt < 4; ++kt) {
      const int row = 64 * g + 16 * w + col;
      const int k0  = 32 * kt + 8 * lq;
      const float* src = (k0 < 64) ? &wih[row * 64 + k0] : &whh[row * 64 + (k0 - 64)];
      float4 v0 = *reinterpret_cast<const float4*>(src);
      float4 v1 = *reinterpret_cast<const float4*>(src + 4);
      float vv[8] = {v0.x, v0.y, v0.z, v0.w, v1.x, v1.y, v1.z, v1.w};
      f16x8 h8;
#pragma unroll
      for (int e = 0; e < 8; ++e) h8[e] = (_Float16)vv[e];
      w16[g][kt] = h8;
    }
#pragma unroll
    for (int r = 0; r < 4; ++r) {
      int row = 64 * g + 16 * w + 4 * lq + r;
      biasf[g][r] = bih[row] + bhh[row];
    }
  }

  __syncthreads();  // hb zeros visible

  // B-frag LDS read offset (halfs): lq*64 + (col&7)*8  (+0 / +256 for kt)
  const int rdoff = lq * 64 + (col & 7) * 8;
  // h write address (halfs): feature f = 16w + 4lq + r ->
  //   kt = w>>1, lq_f = 2(w&1) + (lq>>1), e = 4(lq&1) + r
  const int waddr = (w >> 1) * 256 + (2 * (w & 1) + (lq >> 1)) * 64 +
                    (col & 7) * 8 + 4 * (lq & 1);
  const int feat0 = 16 * w + 4 * lq;
  const bool wr_ok = (col < 8);

  // x prefetch (L0 waves)
  const _Float16* xfl = xf + (size_t)blk * XBLK_HALFS + rdoff;
  f16x8 xb0, xb1, xbn0, xbn1;
  if (L == 0) {
    xb0 = *reinterpret_cast<const f16x8*>(xfl);
    xb1 = *reinterpret_cast<const f16x8*>(xfl + 256);
  }

  f32x4 cst = {0.f, 0.f, 0.f, 0.f};

  for (int t = 0; t <= T_LEN; ++t) {
    const bool act = (L == 0) ? (t < T_LEN) : (t >= 1);

    if (L == 0 && t + 1 < T_LEN) {  // issue x[t+1] load early
      const _Float16* p = xfl + (size_t)(t + 1) * XT_HALFS;
      xbn0 = *reinterpret_cast<const f16x8*>(p);
      xbn1 = *reinterpret_cast<const f16x8*>(p + 256);
    }

    if (act) {
      // B operands
      const _Float16* h0c = &hb[0][(t + 1) & 1][0];  // h0[t-1]
      f16x8 B0, B1, B2, B3;
      if (L == 0) {
        B0 = xb0;
        B1 = xb1;
        B2 = *reinterpret_cast<const f16x8*>(h0c + rdoff);
        B3 = *reinterpret_cast<const f16x8*>(h0c + 256 + rdoff);
      } else {
        const _Float16* h1c = &hb[1][t & 1][0];      // h1[t-2]
        B0 = *reinterpret_cast<const f16x8*>(h0c + rdoff);
        B1 = *reinterpret_cast<const f16x8*>(h0c + 256 + rdoff);
        B2 = *reinterpret_cast<const f16x8*>(h1c + rdoff);
        B3 = *reinterpret_cast<const f16x8*>(h1c + 256 + rdoff);
      }

      // 16 MFMAs: 4 independent gate-chains, round-robin for ILP.
      f32x4 a0 = biasf[0], a1 = biasf[1], a2 = biasf[2], a3 = biasf[3];
      a0 = MFMAH(w16[0][0], B0, a0); a1 = MFMAH(w16[1][0], B0, a1);
      a2 = MFMAH(w16[2][0], B0, a2); a3 = MFMAH(w16[3][0], B0, a3);
      a0 = MFMAH(w16[0][1], B1, a0); a1 = MFMAH(w16[1][1], B1, a1);
      a2 = MFMAH(w16[2][1], B1, a2); a3 = MFMAH(w16[3][1], B1, a3);
      a0 = MFMAH(w16[0][2], B2, a0); a1 = MFMAH(w16[1][2], B2, a1);
      a2 = MFMAH(w16[2][2], B2, a2); a3 = MFMAH(w16[3][2], B2, a3);
      a0 = MFMAH(w16[0][3], B3, a0); a1 = MFMAH(w16[1][3], B3, a1);
      a2 = MFMAH(w16[2][3], B3, a2); a3 = MFMAH(w16[3][3], B3, a3);

      // gates fully in-lane (torch order i,f,g,o); c-state in registers
      f32x4 hv;
#pragma unroll
      for (int r = 0; r < 4; ++r) {
        float ig = sigm_f(a0[r]);
        float fg = sigm_f(a1[r]);
        float gg = tanh_f(a2[r]);
        float og = sigm_f(a3[r]);
        cst[r] = fg * cst[r] + ig * gg;
        hv[r]  = og * tanh_f(cst[r]);
      }

      if (L == 1 && t == T_LEN) {
        if (wr_ok) *reinterpret_cast<f32x4*>(&hfin[col][feat0]) = hv;
      } else if (wr_ok) {
        f16x4 o4;
#pragma unroll
        for (int r = 0; r < 4; ++r) o4[r] = (_Float16)hv[r];
        // L0 writes h0[t] -> buf t&1; L1 writes h1[t-1] -> buf (t+1)&1
        _Float16* base = L ? &hb[1][(t + 1) & 1][0] : &hb[0][t & 1][0];
        *reinterpret_cast<f16x4*>(base + waddr) = o4;
      }
    }

    __syncthreads();  // single barrier per step
    if (L == 0) { xb0 = xbn0; xb1 = xbn1; }
  }

  // ---- FC epilogue: out = fc_w . h2[T-1] + fc_b ----
  if (tid < NCH) {
    float acc = fc_b[0];
#pragma unroll
    for (int h = 0; h < H; ++h) acc += fcw_s[h] * hfin[tid][h];
    out[blk * NCH + tid] = acc;
  }
}

extern "C" void kernel_launch(void* const* d_in, const int* in_sizes, int n_in,
                              void* d_out, int out_size, void* d_ws, size_t ws_size,
                              hipStream_t stream) {
  const float* x     = (const float*)d_in[0];
  const float* w_ih0 = (const float*)d_in[1];
  const float* w_hh0 = (const float*)d_in[2];
  const float* b_ih0 = (const float*)d_in[3];
  const float* b_hh0 = (const float*)d_in[4];
  const float* w_ih1 = (const float*)d_in[5];
  const float* w_hh1 = (const float*)d_in[6];
  const float* b_ih1 = (const float*)d_in[7];
  const float* b_hh1 = (const float*)d_in[8];
  const float* fc_w  = (const float*)d_in[9];
  const float* fc_b  = (const float*)d_in[10];
  float* out = (float*)d_out;

  _Float16* xfrag = (_Float16*)d_ws;  // 64 MiB used

  xconv<<<dim3(8192), dim3(256), 0, stream>>>(x, xfrag);
  lstm_fused<<<dim3(NBLK), dim3(NTHR), 0, stream>>>(
      xfrag, w_ih0, w_hh0, b_ih0, b_hh0, w_ih1, w_hh1, b_ih1, b_hh1,
      fc_w, fc_b, out);
}

// Round 17
// 939.336 us; speedup vs baseline: 1.0161x; 1.0161x over previous
//
#include <hip/hip_runtime.h>
#include <hip/hip_bf16.h>

// LSTMReg on MI355X — round 17: MERGED GATES + HALF-STEP STAGGER (fp16).
// Combines r15's winning property (wave groups in different phases -> MFMA
// and gate pipes co-resident per SIMD) with r16's (z in registers across the
// barrier, bias in regs, no zp LDS, one barrier-hop per layer-step):
//   Interval A: G0 recurrent-MFMA z0(t) (x-side precomputed) || G1 gates on
//               in-reg z1(t-2) -> h1 write.
//   Interval B: G0 gates on in-reg z0(t) -> h0 write, + x-side MFMA for t+1
//               || G1 MFMA z1(t-1) (reads h0[t-1], h1[t-2]).
// 8 waves (wv0-3 G0/L0, wv4-7 G1/L1), NCH=16 (all MFMA cols real), 32 blks.
// Per-value acc order (bias,kt0..kt3) == r15/r16 -> absmax 2.44e-4.

typedef _Float16 f16x8 __attribute__((ext_vector_type(8)));
typedef _Float16 f16x4 __attribute__((ext_vector_type(4)));
typedef float f32x4  __attribute__((ext_vector_type(4)));

#define MFMAH(A, B, C) __builtin_amdgcn_mfma_f32_16x16x32_f16(A, B, C, 0, 0, 0)

constexpr int T_LEN = 1024;
constexpr int H     = 64;
constexpr int NCH   = 16;    // chains per block = all 16 MFMA columns
constexpr int NTHR  = 512;   // 8 waves
constexpr int NBLK  = 32;    // 512 chains / 16

// x fragment buffer: [blk][t][kt(2)][lq(4)][ch(16)][8 halfs]
constexpr int    XT_HALFS   = 2 * 4 * 16 * 8;               // 1024 halfs per t
constexpr size_t XBLK_HALFS = (size_t)T_LEN * XT_HALFS;     // 2 MiB per block

__device__ __forceinline__ float sigm_f(float x) {
  return __builtin_amdgcn_rcpf(1.0f + __expf(-x));
}
__device__ __forceinline__ float tanh_f(float x) {
  return 1.0f - 2.0f * __builtin_amdgcn_rcpf(1.0f + __expf(2.0f * x));
}

// ---- pre-pass: x [512][1024][64] fp32 -> fp16 fragment packets ----
__global__ __launch_bounds__(256, 4) void xconv(const float* __restrict__ x,
                                                _Float16* __restrict__ xf) {
  const int gid = blockIdx.x * 256 + threadIdx.x;  // (chain, t, lq)
  const int lq    = gid & 3;
  const int t     = (gid >> 2) & (T_LEN - 1);
  const int chain = gid >> 12;                     // 0..511
  const int ch  = chain & 15;
  const int blk = chain >> 4;
  const float* src = x + ((size_t)chain * T_LEN + t) * H + 8 * lq;
  float4 v0 = *reinterpret_cast<const float4*>(src);
  float4 v1 = *reinterpret_cast<const float4*>(src + 4);
  float4 v2 = *reinterpret_cast<const float4*>(src + 32);
  float4 v3 = *reinterpret_cast<const float4*>(src + 36);
  float a[8]  = {v0.x, v0.y, v0.z, v0.w, v1.x, v1.y, v1.z, v1.w};
  float c8[8] = {v2.x, v2.y, v2.z, v2.w, v3.x, v3.y, v3.z, v3.w};
  f16x8 p0, p1;
#pragma unroll
  for (int e = 0; e < 8; ++e) {
    p0[e] = (_Float16)a[e];
    p1[e] = (_Float16)c8[e];
  }
  _Float16* dst = xf + (size_t)blk * XBLK_HALFS + (size_t)t * XT_HALFS +
                  lq * 128 + ch * 8;
  *reinterpret_cast<f16x8*>(dst)       = p0;  // kt0 (feats 0-31)
  *reinterpret_cast<f16x8*>(dst + 512) = p1;  // kt1 (feats 32-63)
}

__global__ __launch_bounds__(NTHR, 2) void lstm_fused(
    const _Float16* __restrict__ xf,
    const float* __restrict__ w_ih0, const float* __restrict__ w_hh0,
    const float* __restrict__ b_ih0, const float* __restrict__ b_hh0,
    const float* __restrict__ w_ih1, const float* __restrict__ w_hh1,
    const float* __restrict__ b_ih1, const float* __restrict__ b_hh1,
    const float* __restrict__ fc_w, const float* __restrict__ fc_b,
    float* __restrict__ out) {
  const int tid = threadIdx.x;
  const int wv  = tid >> 6;
  const int G   = wv >> 2;   // 0: L0 waves (wv0-3), 1: L1 waves (wv4-7)
  const int w   = wv & 3;    // feature slice: feats 16w..16w+15 (all 4 gates)
  const int l   = tid & 63;
  const int col = l & 15;    // MFMA column = chain (all 16 real)
  const int lq  = l >> 4;
  const int blk = blockIdx.x;

  // h buffers: [layer][buf][kt(2)][lq(4)][ch(16)][e(8)] halfs = 2 KiB each
  __shared__ __align__(16) _Float16 hb[2][2][1024];
  __shared__ float fcw_s[H];
  __shared__ float hfin[NCH][H];

  for (int i = tid; i < 2 * 2 * 1024; i += NTHR) ((_Float16*)hb)[i] = (_Float16)0.f;
  if (tid < H) fcw_s[tid] = fc_w[tid];

  // ---- weights: gate g tile = rows 64g + 16w + col; k0 = 32kt + 8lq ----
  const float* wih = G ? w_ih1 : w_ih0;
  const float* whh = G ? w_hh1 : w_hh0;
  const float* bih = G ? b_ih1 : b_ih0;
  const float* bhh = G ? b_hh1 : b_hh0;
  f16x8 w16[4][4];  // [gate][kt] = 64 VGPR
  f32x4 biasf[4];   // [gate], per-lane rows 16w + 4lq + r
#pragma unroll
  for (int g = 0; g < 4; ++g) {
#pragma unroll
    for (int kt = 0; kt < 4; ++kt) {
      const int row = 64 * g + 16 * w + col;
      const int k0  = 32 * kt + 8 * lq;
      const float* src = (k0 < 64) ? &wih[row * 64 + k0] : &whh[row * 64 + (k0 - 64)];
      float4 v0 = *reinterpret_cast<const float4*>(src);
      float4 v1 = *reinterpret_cast<const float4*>(src + 4);
      float vv[8] = {v0.x, v0.y, v0.z, v0.w, v1.x, v1.y, v1.z, v1.w};
      f16x8 h8;
#pragma unroll
      for (int e = 0; e < 8; ++e) h8[e] = (_Float16)vv[e];
      w16[g][kt] = h8;
    }
#pragma unroll
    for (int r = 0; r < 4; ++r) {
      int row = 64 * g + 16 * w + 4 * lq + r;
      biasf[g][r] = bih[row] + bhh[row];
    }
  }

  // B-frag LDS read offset (halfs): lq*128 + ch*8 (+512 for kt1)
  const int rdoff = lq * 128 + col * 8;
  // h write (halfs): f = 16w+4lq+r -> kt=w>>1, lqf=2(w&1)+(lq>>1), e=4(lq&1)+r
  const int waddr = (w >> 1) * 512 + (2 * (w & 1) + (lq >> 1)) * 128 +
                    col * 8 + 4 * (lq & 1);
  const int feat0 = 16 * w + 4 * lq;

  // ---- G0 prologue: ax = bias + x-side of step 0; xn1 = x[1] packets ----
  const _Float16* xfl = xf + (size_t)blk * XBLK_HALFS + rdoff;
  f32x4 ax0, ax1, ax2, ax3;       // x-side z accumulators (next G0 step)
  f32x4 a0, a1, a2, a3;           // full z accumulators (live across barrier)
  f16x8 xn1_0, xn1_1, xn2_0, xn2_1;
  if (G == 0) {
    f16x8 xq0 = *reinterpret_cast<const f16x8*>(xfl);
    f16x8 xq1 = *reinterpret_cast<const f16x8*>(xfl + 512);
    ax0 = biasf[0]; ax1 = biasf[1]; ax2 = biasf[2]; ax3 = biasf[3];
    ax0 = MFMAH(w16[0][0], xq0, ax0); ax1 = MFMAH(w16[1][0], xq0, ax1);
    ax2 = MFMAH(w16[2][0], xq0, ax2); ax3 = MFMAH(w16[3][0], xq0, ax3);
    ax0 = MFMAH(w16[0][1], xq1, ax0); ax1 = MFMAH(w16[1][1], xq1, ax1);
    ax2 = MFMAH(w16[2][1], xq1, ax2); ax3 = MFMAH(w16[3][1], xq1, ax3);
    const _Float16* p = xfl + XT_HALFS;  // x[1]
    xn1_0 = *reinterpret_cast<const f16x8*>(p);
    xn1_1 = *reinterpret_cast<const f16x8*>(p + 512);
  }

  f32x4 cst = {0.f, 0.f, 0.f, 0.f};

#define GATES(hv_)                                                  \
  {                                                                 \
    _Pragma("unroll")                                               \
    for (int r = 0; r < 4; ++r) {                                   \
      float ig = sigm_f(a0[r]);                                     \
      float fg = sigm_f(a1[r]);                                     \
      float gg = tanh_f(a2[r]);                                     \
      float og = sigm_f(a3[r]);                                     \
      cst[r] = fg * cst[r] + ig * gg;                               \
      hv_[r] = og * tanh_f(cst[r]);                                 \
    }                                                               \
  }

#define HSTORE(base_, hv_)                                          \
  {                                                                 \
    f16x4 o4;                                                       \
    _Pragma("unroll")                                               \
    for (int r = 0; r < 4; ++r) o4[r] = (_Float16)hv_[r];           \
    *reinterpret_cast<f16x4*>((base_) + waddr) = o4;                \
  }

  __syncthreads();  // hb zeros visible

  for (int t = 0; t <= T_LEN + 1; ++t) {
    // ===== Interval A: G0 recurrent-MFMA z0(t) || G1 gates z1(t-2) =====
    if (G == 0) {
      if (t + 2 < T_LEN) {  // issue x[t+2] loads (consumed interval B, t+1)
        const _Float16* p = xfl + (size_t)(t + 2) * XT_HALFS;
        xn2_0 = *reinterpret_cast<const f16x8*>(p);
        xn2_1 = *reinterpret_cast<const f16x8*>(p + 512);
      }
      if (t < T_LEN) {
        const _Float16* h0c = &hb[0][(t + 1) & 1][0];  // h0[t-1]
        f16x8 B2 = *reinterpret_cast<const f16x8*>(h0c + rdoff);
        f16x8 B3 = *reinterpret_cast<const f16x8*>(h0c + 512 + rdoff);
        a0 = MFMAH(w16[0][2], B2, ax0); a1 = MFMAH(w16[1][2], B2, ax1);
        a2 = MFMAH(w16[2][2], B2, ax2); a3 = MFMAH(w16[3][2], B2, ax3);
        a0 = MFMAH(w16[0][3], B3, a0);  a1 = MFMAH(w16[1][3], B3, a1);
        a2 = MFMAH(w16[2][3], B3, a2);  a3 = MFMAH(w16[3][3], B3, a3);
      }
    } else {
      if (t >= 2) {  // gates on in-reg z1(t-2)
        f32x4 hv;
        GATES(hv)
        if (t == T_LEN + 1) {
          *reinterpret_cast<f32x4*>(&hfin[col][feat0]) = hv;
        } else {
          HSTORE(&hb[1][t & 1][0], hv)  // h1[t-2] -> buf (t-2)&1 == t&1
        }
      }
    }

    __syncthreads();

    // ===== Interval B: G0 gates z0(t) + x-side(t+1) || G1 MFMA z1(t-1) =====
    if (G == 0) {
      if (t < T_LEN) {
        f32x4 hv;
        GATES(hv)
        HSTORE(&hb[0][t & 1][0], hv)    // h0[t]
      }
      if (t + 1 < T_LEN) {  // x-side precompute for step t+1 (overlaps gates)
        ax0 = biasf[0]; ax1 = biasf[1]; ax2 = biasf[2]; ax3 = biasf[3];
        ax0 = MFMAH(w16[0][0], xn1_0, ax0); ax1 = MFMAH(w16[1][0], xn1_0, ax1);
        ax2 = MFMAH(w16[2][0], xn1_0, ax2); ax3 = MFMAH(w16[3][0], xn1_0, ax3);
        ax0 = MFMAH(w16[0][1], xn1_1, ax0); ax1 = MFMAH(w16[1][1], xn1_1, ax1);
        ax2 = MFMAH(w16[2][1], xn1_1, ax2); ax3 = MFMAH(w16[3][1], xn1_1, ax3);
      }
    } else {
      if (t >= 1 && t <= T_LEN) {  // z1(t-1): h0[t-1] + h1[t-2]
        const _Float16* h0c = &hb[0][(t + 1) & 1][0];
        const _Float16* h1c = &hb[1][t & 1][0];
        f16x8 B0 = *reinterpret_cast<const f16x8*>(h0c + rdoff);
        f16x8 B1 = *reinterpret_cast<const f16x8*>(h0c + 512 + rdoff);
        f16x8 B2 = *reinterpret_cast<const f16x8*>(h1c + rdoff);
        f16x8 B3 = *reinterpret_cast<const f16x8*>(h1c + 512 + rdoff);
        a0 = biasf[0]; a1 = biasf[1]; a2 = biasf[2]; a3 = biasf[3];
        a0 = MFMAH(w16[0][0], B0, a0); a1 = MFMAH(w16[1][0], B0, a1);
        a2 = MFMAH(w16[2][0], B0, a2); a3 = MFMAH(w16[3][0], B0, a3);
        a0 = MFMAH(w16[0][1], B1, a0); a1 = MFMAH(w16[1][1], B1, a1);
        a2 = MFMAH(w16[2][1], B1, a2); a3 = MFMAH(w16[3][1], B1, a3);
        a0 = MFMAH(w16[0][2], B2, a0); a1 = MFMAH(w16[1][2], B2, a1);
        a2 = MFMAH(w16[2][2], B2, a2); a3 = MFMAH(w16[3][2], B2, a3);
        a0 = MFMAH(w16[0][3], B3, a0); a1 = MFMAH(w16[1][3], B3, a1);
        a2 = MFMAH(w16[2][3], B3, a2); a3 = MFMAH(w16[3][3], B3, a3);
      }
    }

    __syncthreads();
    if (G == 0) { xn1_0 = xn2_0; xn1_1 = xn2_1; }
  }
#undef GATES
#undef HSTORE

  // ---- FC epilogue: out = fc_w . h2[T-1] + fc_b ----
  if (tid < NCH) {
    float acc = fc_b[0];
#pragma unroll
    for (int h = 0; h < H; ++h) acc += fcw_s[h] * hfin[tid][h];
    out[blk * NCH + tid] = acc;
  }
}

extern "C" void kernel_launch(void* const* d_in, const int* in_sizes, int n_in,
                              void* d_out, int out_size, void* d_ws, size_t ws_size,
                              hipStream_t stream) {
  const float* x     = (const float*)d_in[0];
  const float* w_ih0 = (const float*)d_in[1];
  const float* w_hh0 = (const float*)d_in[2];
  const float* b_ih0 = (const float*)d_in[3];
  const float* b_hh0 = (const float*)d_in[4];
  const float* w_ih1 = (const float*)d_in[5];
  const float* w_hh1 = (const float*)d_in[6];
  const float* b_ih1 = (const float*)d_in[7];
  const float* b_hh1 = (const float*)d_in[8];
  const float* fc_w  = (const float*)d_in[9];
  const float* fc_b  = (const float*)d_in[10];
  float* out = (float*)d_out;

  _Float16* xfrag = (_Float16*)d_ws;  // 64 MiB used

  xconv<<<dim3(8192), dim3(256), 0, stream>>>(x, xfrag);
  lstm_fused<<<dim3(NBLK), dim3(NTHR), 0, stream>>>(
      xfrag, w_ih0, w_hh0, b_ih0, b_hh0, w_ih1, w_hh1, b_ih1, b_hh1,
      fc_w, fc_b, out);
}

// Round 18
// 939.091 us; speedup vs baseline: 1.0163x; 1.0003x over previous
//
#include <hip/hip_runtime.h>
#include <hip/hip_bf16.h>

// LSTMReg on MI355X — round 18: r17 + RAW LDS-ONLY BARRIERS.
// r17 audit: per-iter work (32 MFMA/SIMD ~620 cyc + gates ~300) accounts for
// barely half of the measured 2100 cyc. The residual: __syncthreads() emits
// s_waitcnt vmcnt(0) lgkmcnt(0) + s_barrier, force-draining G0's x-prefetch
// global loads at BOTH barriers every iteration (the guide's documented
// ~20% barrier-drain stall, here 2x per step on a serial recurrence).
// Fix: in-loop barriers become {s_waitcnt lgkmcnt(0); s_barrier} — LDS
// ordering preserved (writer drains lgkm before barrier), global x loads
// stay in flight across barriers and are waited only at use (vmcnt at MFMA).
// Schedule/maps/arithmetic identical to r17 -> absmax 2.441e-4.

typedef _Float16 f16x8 __attribute__((ext_vector_type(8)));
typedef _Float16 f16x4 __attribute__((ext_vector_type(4)));
typedef float f32x4  __attribute__((ext_vector_type(4)));

#define MFMAH(A, B, C) __builtin_amdgcn_mfma_f32_16x16x32_f16(A, B, C, 0, 0, 0)

constexpr int T_LEN = 1024;
constexpr int H     = 64;
constexpr int NCH   = 16;    // chains per block = all 16 MFMA columns
constexpr int NTHR  = 512;   // 8 waves
constexpr int NBLK  = 32;    // 512 chains / 16

// x fragment buffer: [blk][t][kt(2)][lq(4)][ch(16)][8 halfs]
constexpr int    XT_HALFS   = 2 * 4 * 16 * 8;               // 1024 halfs per t
constexpr size_t XBLK_HALFS = (size_t)T_LEN * XT_HALFS;     // 2 MiB per block

__device__ __forceinline__ float sigm_f(float x) {
  return __builtin_amdgcn_rcpf(1.0f + __expf(-x));
}
__device__ __forceinline__ float tanh_f(float x) {
  return 1.0f - 2.0f * __builtin_amdgcn_rcpf(1.0f + __expf(2.0f * x));
}
// LDS-only barrier: drain LDS ops, NOT outstanding global loads (vmcnt).
__device__ __forceinline__ void lds_barrier() {
  asm volatile("s_waitcnt lgkmcnt(0)" ::: "memory");
  __builtin_amdgcn_s_barrier();
  asm volatile("" ::: "memory");
}

// ---- pre-pass: x [512][1024][64] fp32 -> fp16 fragment packets ----
__global__ __launch_bounds__(256, 4) void xconv(const float* __restrict__ x,
                                                _Float16* __restrict__ xf) {
  const int gid = blockIdx.x * 256 + threadIdx.x;  // (chain, t, lq)
  const int lq    = gid & 3;
  const int t     = (gid >> 2) & (T_LEN - 1);
  const int chain = gid >> 12;                     // 0..511
  const int ch  = chain & 15;
  const int blk = chain >> 4;
  const float* src = x + ((size_t)chain * T_LEN + t) * H + 8 * lq;
  float4 v0 = *reinterpret_cast<const float4*>(src);
  float4 v1 = *reinterpret_cast<const float4*>(src + 4);
  float4 v2 = *reinterpret_cast<const float4*>(src + 32);
  float4 v3 = *reinterpret_cast<const float4*>(src + 36);
  float a[8]  = {v0.x, v0.y, v0.z, v0.w, v1.x, v1.y, v1.z, v1.w};
  float c8[8] = {v2.x, v2.y, v2.z, v2.w, v3.x, v3.y, v3.z, v3.w};
  f16x8 p0, p1;
#pragma unroll
  for (int e = 0; e < 8; ++e) {
    p0[e] = (_Float16)a[e];
    p1[e] = (_Float16)c8[e];
  }
  _Float16* dst = xf + (size_t)blk * XBLK_HALFS + (size_t)t * XT_HALFS +
                  lq * 128 + ch * 8;
  *reinterpret_cast<f16x8*>(dst)       = p0;  // kt0 (feats 0-31)
  *reinterpret_cast<f16x8*>(dst + 512) = p1;  // kt1 (feats 32-63)
}

__global__ __launch_bounds__(NTHR, 2) void lstm_fused(
    const _Float16* __restrict__ xf,
    const float* __restrict__ w_ih0, const float* __restrict__ w_hh0,
    const float* __restrict__ b_ih0, const float* __restrict__ b_hh0,
    const float* __restrict__ w_ih1, const float* __restrict__ w_hh1,
    const float* __restrict__ b_ih1, const float* __restrict__ b_hh1,
    const float* __restrict__ fc_w, const float* __restrict__ fc_b,
    float* __restrict__ out) {
  const int tid = threadIdx.x;
  const int wv  = tid >> 6;
  const int G   = wv >> 2;   // 0: L0 waves (wv0-3), 1: L1 waves (wv4-7)
  const int w   = wv & 3;    // feature slice: feats 16w..16w+15 (all 4 gates)
  const int l   = tid & 63;
  const int col = l & 15;    // MFMA column = chain (all 16 real)
  const int lq  = l >> 4;
  const int blk = blockIdx.x;

  // h buffers: [layer][buf][kt(2)][lq(4)][ch(16)][e(8)] halfs = 2 KiB each
  __shared__ __align__(16) _Float16 hb[2][2][1024];
  __shared__ float fcw_s[H];
  __shared__ float hfin[NCH][H];

  for (int i = tid; i < 2 * 2 * 1024; i += NTHR) ((_Float16*)hb)[i] = (_Float16)0.f;
  if (tid < H) fcw_s[tid] = fc_w[tid];

  // ---- weights: gate g tile = rows 64g + 16w + col; k0 = 32kt + 8lq ----
  const float* wih = G ? w_ih1 : w_ih0;
  const float* whh = G ? w_hh1 : w_hh0;
  const float* bih = G ? b_ih1 : b_ih0;
  const float* bhh = G ? b_hh1 : b_hh0;
  f16x8 w16[4][4];  // [gate][kt] = 64 VGPR
  f32x4 biasf[4];   // [gate], per-lane rows 16w + 4lq + r
#pragma unroll
  for (int g = 0; g < 4; ++g) {
#pragma unroll
    for (int kt = 0; kt < 4; ++kt) {
      const int row = 64 * g + 16 * w + col;
      const int k0  = 32 * kt + 8 * lq;
      const float* src = (k0 < 64) ? &wih[row * 64 + k0] : &whh[row * 64 + (k0 - 64)];
      float4 v0 = *reinterpret_cast<const float4*>(src);
      float4 v1 = *reinterpret_cast<const float4*>(src + 4);
      float vv[8] = {v0.x, v0.y, v0.z, v0.w, v1.x, v1.y, v1.z, v1.w};
      f16x8 h8;
#pragma unroll
      for (int e = 0; e < 8; ++e) h8[e] = (_Float16)vv[e];
      w16[g][kt] = h8;
    }
#pragma unroll
    for (int r = 0; r < 4; ++r) {
      int row = 64 * g + 16 * w + 4 * lq + r;
      biasf[g][r] = bih[row] + bhh[row];
    }
  }

  // B-frag LDS read offset (halfs): lq*128 + ch*8 (+512 for kt1)
  const int rdoff = lq * 128 + col * 8;
  // h write (halfs): f = 16w+4lq+r -> kt=w>>1, lqf=2(w&1)+(lq>>1), e=4(lq&1)+r
  const int waddr = (w >> 1) * 512 + (2 * (w & 1) + (lq >> 1)) * 128 +
                    col * 8 + 4 * (lq & 1);
  const int feat0 = 16 * w + 4 * lq;

  // ---- G0 prologue: ax = bias + x-side of step 0; xn1 = x[1] packets ----
  const _Float16* xfl = xf + (size_t)blk * XBLK_HALFS + rdoff;
  f32x4 ax0, ax1, ax2, ax3;       // x-side z accumulators (next G0 step)
  f32x4 a0, a1, a2, a3;           // full z accumulators (live across barrier)
  f16x8 xn1_0, xn1_1, xn2_0, xn2_1;
  if (G == 0) {
    f16x8 xq0 = *reinterpret_cast<const f16x8*>(xfl);
    f16x8 xq1 = *reinterpret_cast<const f16x8*>(xfl + 512);
    ax0 = biasf[0]; ax1 = biasf[1]; ax2 = biasf[2]; ax3 = biasf[3];
    ax0 = MFMAH(w16[0][0], xq0, ax0); ax1 = MFMAH(w16[1][0], xq0, ax1);
    ax2 = MFMAH(w16[2][0], xq0, ax2); ax3 = MFMAH(w16[3][0], xq0, ax3);
    ax0 = MFMAH(w16[0][1], xq1, ax0); ax1 = MFMAH(w16[1][1], xq1, ax1);
    ax2 = MFMAH(w16[2][1], xq1, ax2); ax3 = MFMAH(w16[3][1], xq1, ax3);
    const _Float16* p = xfl + XT_HALFS;  // x[1]
    xn1_0 = *reinterpret_cast<const f16x8*>(p);
    xn1_1 = *reinterpret_cast<const f16x8*>(p + 512);
  }

  f32x4 cst = {0.f, 0.f, 0.f, 0.f};

#define GATES(hv_)                                                  \
  {                                                                 \
    _Pragma("unroll")                                               \
    for (int r = 0; r < 4; ++r) {                                   \
      float ig = sigm_f(a0[r]);                                     \
      float fg = sigm_f(a1[r]);                                     \
      float gg = tanh_f(a2[r]);                                     \
      float og = sigm_f(a3[r]);                                     \
      cst[r] = fg * cst[r] + ig * gg;                               \
      hv_[r] = og * tanh_f(cst[r]);                                 \
    }                                                               \
  }

#define HSTORE(base_, hv_)                                          \
  {                                                                 \
    f16x4 o4;                                                       \
    _Pragma("unroll")                                               \
    for (int r = 0; r < 4; ++r) o4[r] = (_Float16)hv_[r];           \
    *reinterpret_cast<f16x4*>((base_) + waddr) = o4;                \
  }

  __syncthreads();  // one-time: hb zeros / fcw visible (full drain is fine)

  for (int t = 0; t <= T_LEN + 1; ++t) {
    // ===== Interval A: G0 recurrent-MFMA z0(t) || G1 gates z1(t-2) =====
    if (G == 0) {
      if (t + 2 < T_LEN) {  // issue x[t+2] loads (stay in flight across barriers)
        const _Float16* p = xfl + (size_t)(t + 2) * XT_HALFS;
        xn2_0 = *reinterpret_cast<const f16x8*>(p);
        xn2_1 = *reinterpret_cast<const f16x8*>(p + 512);
      }
      if (t < T_LEN) {
        const _Float16* h0c = &hb[0][(t + 1) & 1][0];  // h0[t-1]
        f16x8 B2 = *reinterpret_cast<const f16x8*>(h0c + rdoff);
        f16x8 B3 = *reinterpret_cast<const f16x8*>(h0c + 512 + rdoff);
        a0 = MFMAH(w16[0][2], B2, ax0); a1 = MFMAH(w16[1][2], B2, ax1);
        a2 = MFMAH(w16[2][2], B2, ax2); a3 = MFMAH(w16[3][2], B2, ax3);
        a0 = MFMAH(w16[0][3], B3, a0);  a1 = MFMAH(w16[1][3], B3, a1);
        a2 = MFMAH(w16[2][3], B3, a2);  a3 = MFMAH(w16[3][3], B3, a3);
      }
    } else {
      if (t >= 2) {  // gates on in-reg z1(t-2)
        f32x4 hv;
        GATES(hv)
        if (t == T_LEN + 1) {
          *reinterpret_cast<f32x4*>(&hfin[col][feat0]) = hv;
        } else {
          HSTORE(&hb[1][t & 1][0], hv)  // h1[t-2] -> buf (t-2)&1 == t&1
        }
      }
    }

    lds_barrier();

    // ===== Interval B: G0 gates z0(t) + x-side(t+1) || G1 MFMA z1(t-1) =====
    if (G == 0) {
      if (t < T_LEN) {
        f32x4 hv;
        GATES(hv)
        HSTORE(&hb[0][t & 1][0], hv)    // h0[t]
      }
      if (t + 1 < T_LEN) {  // x-side precompute for step t+1 (overlaps gates)
        ax0 = biasf[0]; ax1 = biasf[1]; ax2 = biasf[2]; ax3 = biasf[3];
        ax0 = MFMAH(w16[0][0], xn1_0, ax0); ax1 = MFMAH(w16[1][0], xn1_0, ax1);
        ax2 = MFMAH(w16[2][0], xn1_0, ax2); ax3 = MFMAH(w16[3][0], xn1_0, ax3);
        ax0 = MFMAH(w16[0][1], xn1_1, ax0); ax1 = MFMAH(w16[1][1], xn1_1, ax1);
        ax2 = MFMAH(w16[2][1], xn1_1, ax2); ax3 = MFMAH(w16[3][1], xn1_1, ax3);
      }
    } else {
      if (t >= 1 && t <= T_LEN) {  // z1(t-1): h0[t-1] + h1[t-2]
        const _Float16* h0c = &hb[0][(t + 1) & 1][0];
        const _Float16* h1c = &hb[1][t & 1][0];
        f16x8 B0 = *reinterpret_cast<const f16x8*>(h0c + rdoff);
        f16x8 B1 = *reinterpret_cast<const f16x8*>(h0c + 512 + rdoff);
        f16x8 B2 = *reinterpret_cast<const f16x8*>(h1c + rdoff);
        f16x8 B3 = *reinterpret_cast<const f16x8*>(h1c + 512 + rdoff);
        a0 = biasf[0]; a1 = biasf[1]; a2 = biasf[2]; a3 = biasf[3];
        a0 = MFMAH(w16[0][0], B0, a0); a1 = MFMAH(w16[1][0], B0, a1);
        a2 = MFMAH(w16[2][0], B0, a2); a3 = MFMAH(w16[3][0], B0, a3);
        a0 = MFMAH(w16[0][1], B1, a0); a1 = MFMAH(w16[1][1], B1, a1);
        a2 = MFMAH(w16[2][1], B1, a2); a3 = MFMAH(w16[3][1], B1, a3);
        a0 = MFMAH(w16[0][2], B2, a0); a1 = MFMAH(w16[1][2], B2, a1);
        a2 = MFMAH(w16[2][2], B2, a2); a3 = MFMAH(w16[3][2], B2, a3);
        a0 = MFMAH(w16[0][3], B3, a0); a1 = MFMAH(w16[1][3], B3, a1);
        a2 = MFMAH(w16[2][3], B3, a2); a3 = MFMAH(w16[3][3], B3, a3);
      }
    }

    lds_barrier();
    if (G == 0) { xn1_0 = xn2_0; xn1_1 = xn2_1; }
  }
#undef GATES
#undef HSTORE

  // ---- FC epilogue: out = fc_w . h2[T-1] + fc_b ----
  if (tid < NCH) {
    float acc = fc_b[0];
#pragma unroll
    for (int h = 0; h < H; ++h) acc += fcw_s[h] * hfin[tid][h];
    out[blk * NCH + tid] = acc;
  }
}

extern "C" void kernel_launch(void* const* d_in, const int* in_sizes, int n_in,
                              void* d_out, int out_size, void* d_ws, size_t ws_size,
                              hipStream_t stream) {
  const float* x     = (const float*)d_in[0];
  const float* w_ih0 = (const float*)d_in[1];
  const float* w_hh0 = (const float*)d_in[2];
  const float* b_ih0 = (const float*)d_in[3];
  const float* b_hh0 = (const float*)d_in[4];
  const float* w_ih1 = (const float*)d_in[5];
  const float* w_hh1 = (const float*)d_in[6];
  const float* b_ih1 = (const float*)d_in[7];
  const float* b_hh1 = (const float*)d_in[8];
  const float* fc_w  = (const float*)d_in[9];
  const float* fc_b  = (const float*)d_in[10];
  float* out = (float*)d_out;

  _Float16* xfrag = (_Float16*)d_ws;  // 64 MiB used

  xconv<<<dim3(8192), dim3(256), 0, stream>>>(x, xfrag);
  lstm_fused<<<dim3(NBLK), dim3(NTHR), 0, stream>>>(
      xfrag, w_ih0, w_hh0, b_ih0, b_hh0, w_ih1, w_hh1, b_ih1, b_hh1,
      fc_w, fc_b, out);
}

// Round 19
// 787.961 us; speedup vs baseline: 1.2113x; 1.1918x over previous
//
#include <hip/hip_runtime.h>
#include <hip/hip_bf16.h>

// LSTMReg on MI355X — round 19: SPREAD TO ALL 256 CUs (NCH=2) on the r15
// champion skeleton. Law from r9-r18: time tracks waves/SIMD + per-SIMD
// VALU(trans)+MFMA load. Per-SIMD MFMA is invariant to spreading (cols
// duplicate); per-SIMD transcendental load = total/activeSIMDs -> 4x cut by
// going 64->256 blocks. Keep r15's 16-wave 4/SIMD staggered 2-phase:
//   Phase A: L0 waves (0-7) MFMA z0(t) -> zp[0] || wv10,11 gates L1(t-2)
//   Phase B: wv0,1 gates L0(t) || L1 waves (8-15) MFMA z1(t-1) -> zp[1]
// One gate wave per SIMD, hidden under 3 MFMA waves. All maps = r15's
// verified maps with ch width 8->2; operand-identical per chain ->
// absmax must be exactly 2.441406e-4 (correctness check).

typedef _Float16 f16x8 __attribute__((ext_vector_type(8)));
typedef float f32x4  __attribute__((ext_vector_type(4)));

#define MFMAH(A, B, C) __builtin_amdgcn_mfma_f32_16x16x32_f16(A, B, C, 0, 0, 0)

constexpr int T_LEN = 1024;
constexpr int H     = 64;
constexpr int NCH   = 2;     // chains per block -> 256 blocks = all CUs
constexpr int NTHR  = 1024;  // 16 waves = 4/SIMD
constexpr int NBLK  = 256;

// x fragment buffer: [blk][t][kt(2)][lq(4)][ch(2)][8 halfs]
constexpr int    XT_HALFS   = 2 * 4 * 2 * 8;                // 128 halfs per t
constexpr size_t XBLK_HALFS = (size_t)T_LEN * XT_HALFS;     // 256 KiB per block

__device__ __forceinline__ float sigm_f(float x) {
  return __builtin_amdgcn_rcpf(1.0f + __expf(-x));
}
__device__ __forceinline__ float tanh_f(float x) {
  return 1.0f - 2.0f * __builtin_amdgcn_rcpf(1.0f + __expf(2.0f * x));
}
__device__ __forceinline__ unsigned dpp_xor1_u32(unsigned v) {
  return (unsigned)__builtin_amdgcn_mov_dpp((int)v, 0xB1, 0xF, 0xF, true);
}
// LDS-only barrier (r18: neutral vs __syncthreads, keeps x loads in flight)
__device__ __forceinline__ void lds_barrier() {
  asm volatile("s_waitcnt lgkmcnt(0)" ::: "memory");
  __builtin_amdgcn_s_barrier();
  asm volatile("" ::: "memory");
}

// ---- pre-pass: x [512][1024][64] fp32 -> fp16 fragment packets ----
__global__ __launch_bounds__(256, 4) void xconv(const float* __restrict__ x,
                                                _Float16* __restrict__ xf) {
  const int gid = blockIdx.x * 256 + threadIdx.x;  // (chain, t, lq)
  const int lq    = gid & 3;
  const int t     = (gid >> 2) & (T_LEN - 1);
  const int chain = gid >> 12;                     // 0..511
  const int ch  = chain & 1;
  const int blk = chain >> 1;
  const float* src = x + ((size_t)chain * T_LEN + t) * H + 8 * lq;
  float4 v0 = *reinterpret_cast<const float4*>(src);
  float4 v1 = *reinterpret_cast<const float4*>(src + 4);
  float4 v2 = *reinterpret_cast<const float4*>(src + 32);
  float4 v3 = *reinterpret_cast<const float4*>(src + 36);
  float a[8]  = {v0.x, v0.y, v0.z, v0.w, v1.x, v1.y, v1.z, v1.w};
  float c8[8] = {v2.x, v2.y, v2.z, v2.w, v3.x, v3.y, v3.z, v3.w};
  f16x8 p0, p1;
#pragma unroll
  for (int e = 0; e < 8; ++e) {
    p0[e] = (_Float16)a[e];
    p1[e] = (_Float16)c8[e];
  }
  _Float16* dst = xf + (size_t)blk * XBLK_HALFS + (size_t)t * XT_HALFS +
                  lq * 16 + ch * 8;
  *reinterpret_cast<f16x8*>(dst)      = p0;  // kt0 (feats 0-31)
  *reinterpret_cast<f16x8*>(dst + 64) = p1;  // kt1 (feats 32-63)
}

__global__ __launch_bounds__(NTHR) void lstm_fused(
    const _Float16* __restrict__ xf,
    const float* __restrict__ w_ih0, const float* __restrict__ w_hh0,
    const float* __restrict__ b_ih0, const float* __restrict__ b_hh0,
    const float* __restrict__ w_ih1, const float* __restrict__ w_hh1,
    const float* __restrict__ b_ih1, const float* __restrict__ b_hh1,
    const float* __restrict__ fc_w, const float* __restrict__ fc_b,
    float* __restrict__ out) {
  const int tid = threadIdx.x;
  const int wv  = tid >> 6;
  const int L   = wv >> 3;   // 0: L0 waves (wv0-7), 1: L1 waves (wv8-15)
  const int w8  = wv & 7;    // row-block: rows [32*w8, 32*w8+32)
  const int l   = tid & 63;
  const int col = l & 15;    // MFMA column; chain = col&1 (8x duplicated)
  const int lq  = l >> 4;
  const int blk = blockIdx.x;

  // h buffers: [layer][buf][kt(2)][lq(4)][ch(2)][e(8)] = 128 halfs per buf
  __shared__ __align__(16) _Float16 hb[2][2][128];
  __shared__ __align__(16) float zp[2][2][260];   // [L][chain][row(+pad)]
  __shared__ float bias_s[2][256];
  __shared__ float fcw_s[H];
  __shared__ float hfin[NCH][H];

  for (int i = tid; i < 2 * 2 * 128; i += NTHR) ((_Float16*)hb)[i] = (_Float16)0.f;
  if (tid < 256)       bias_s[0][tid] = b_ih0[tid] + b_hh0[tid];
  else if (tid < 512)  bias_s[1][tid - 256] = b_ih1[tid - 256] + b_hh1[tid - 256];
  if (tid < H) fcw_s[tid] = fc_w[tid];

  // ---- weights: rows 32*w8 + 16*rt + col; k0 = 32kt + 8lq (= r15 map) ----
  const float* wih = L ? w_ih1 : w_ih0;
  const float* whh = L ? w_hh1 : w_hh0;
  f16x8 w16[2][4];  // [rt][kt] = 32 VGPR
#pragma unroll
  for (int rt = 0; rt < 2; ++rt) {
#pragma unroll
    for (int kt = 0; kt < 4; ++kt) {
      const int row = 32 * w8 + 16 * rt + col;
      const int k0  = 32 * kt + 8 * lq;
      const float* src = (k0 < 64) ? &wih[row * 64 + k0] : &whh[row * 64 + (k0 - 64)];
      float4 v0 = *reinterpret_cast<const float4*>(src);
      float4 v1 = *reinterpret_cast<const float4*>(src + 4);
      float vv[8] = {v0.x, v0.y, v0.z, v0.w, v1.x, v1.y, v1.z, v1.w};
      f16x8 h8;
#pragma unroll
      for (int e = 0; e < 8; ++e) h8[e] = (_Float16)vv[e];
      w16[rt][kt] = h8;
    }
  }

  // B-frag LDS read offset (halfs): lq*16 + (col&1)*8  (+64 for kt1)
  const int rdoff = lq * 16 + (col & 1) * 8;
  // gate waves: wv0(S0),wv1(S1) for L0; wv10(S2),wv11(S3) for L1
  const bool is_gate = (wv < 2) || (wv == 10) || (wv == 11);
  const int gch = wv & 1;    // chain
  const int gh  = l;         // feature
  // h write addr (halfs): f=gh -> kt=gh>>5, lq=(gh>>3)&3, e=gh&7
  const int waddr_h = ((gh >> 5) << 6) + (((gh >> 3) & 3) << 4) + (gch << 3) + (gh & 7);
  float cst = 0.0f;

  // x prefetch (L0 waves)
  const _Float16* xfl = xf + (size_t)blk * XBLK_HALFS + rdoff;
  f16x8 xb0, xb1, xbn0, xbn1;
  if (L == 0) {
    xb0 = *reinterpret_cast<const f16x8*>(xfl);
    xb1 = *reinterpret_cast<const f16x8*>(xfl + 64);
  }

  const f32x4 zf4 = {0.f, 0.f, 0.f, 0.f};

#define GATES(Lidx, hv_)                                            \
  {                                                                 \
    const float* zrow = &zp[Lidx][gch][0];                          \
    float z0 = zrow[gh]       + bias_s[Lidx][gh];                   \
    float z1 = zrow[64 + gh]  + bias_s[Lidx][64 + gh];              \
    float z2 = zrow[128 + gh] + bias_s[Lidx][128 + gh];             \
    float z3 = zrow[192 + gh] + bias_s[Lidx][192 + gh];             \
    float ig = sigm_f(z0), fg = sigm_f(z1);                         \
    float gg = tanh_f(z2), og = sigm_f(z3);                         \
    cst = fg * cst + ig * gg;                                       \
    hv_ = og * tanh_f(cst);                                         \
  }

  // even lane packs (own, neighbor) halves -> one b32 write
#define HSTORE(base_, hv_)                                          \
  {                                                                 \
    _Float16 hf = (_Float16)(hv_);                                  \
    unsigned me = (unsigned)__builtin_bit_cast(unsigned short, hf); \
    unsigned nb = dpp_xor1_u32(me);                                 \
    if ((l & 1) == 0)                                               \
      reinterpret_cast<unsigned*>(base_)[waddr_h >> 1] = me | (nb << 16); \
  }

  __syncthreads();  // hb zeros / bias visible

  for (int t = 0; t <= T_LEN + 1; ++t) {
    // ===== Phase A: L0 MFMA z0(t) -> zp[0] || wv10,11 gates L1(t-2) =====
    if (L == 0) {
      if (t + 1 < T_LEN) {  // issue x[t+1] loads (stay in flight)
        const _Float16* p = xfl + (size_t)(t + 1) * XT_HALFS;
        xbn0 = *reinterpret_cast<const f16x8*>(p);
        xbn1 = *reinterpret_cast<const f16x8*>(p + 64);
      }
      if (t < T_LEN) {
        const _Float16* h0c = &hb[0][(t + 1) & 1][0];  // h0[t-1]
        f16x8 B2 = *reinterpret_cast<const f16x8*>(h0c + rdoff);
        f16x8 B3 = *reinterpret_cast<const f16x8*>(h0c + 64 + rdoff);
        f32x4 a0 = zf4, a1 = zf4;
        a0 = MFMAH(w16[0][0], xb0, a0); a1 = MFMAH(w16[1][0], xb0, a1);
        a0 = MFMAH(w16[0][1], xb1, a0); a1 = MFMAH(w16[1][1], xb1, a1);
        a0 = MFMAH(w16[0][2], B2,  a0); a1 = MFMAH(w16[1][2], B2,  a1);
        a0 = MFMAH(w16[0][3], B3,  a0); a1 = MFMAH(w16[1][3], B3,  a1);
        if (col < NCH) {
          *reinterpret_cast<f32x4*>(&zp[0][col][32 * w8 + 4 * lq])      = a0;
          *reinterpret_cast<f32x4*>(&zp[0][col][32 * w8 + 16 + 4 * lq]) = a1;
        }
      }
    } else if (is_gate) {  // wv10, wv11: gates L1 step t-2
      if (t >= 2) {
        float hv;
        GATES(1, hv)
        if (t == T_LEN + 1) {
          hfin[gch][gh] = hv;
        } else {
          HSTORE(&hb[1][t & 1][0], hv)  // h1[t-2] -> buf (t-2)&1 == t&1
        }
      }
    }

    lds_barrier();

    // ===== Phase B: wv0,1 gates L0(t) || L1 MFMA z1(t-1) -> zp[1] =====
    if (L == 0) {
      if (is_gate && t < T_LEN) {
        float hv;
        GATES(0, hv)
        HSTORE(&hb[0][t & 1][0], hv)    // h0[t]
      }
    } else {
      if (t >= 1 && t <= T_LEN) {
        const _Float16* h0c = &hb[0][(t + 1) & 1][0];  // h0[t-1]
        const _Float16* h1c = &hb[1][t & 1][0];        // h1[t-2]
        f16x8 B0 = *reinterpret_cast<const f16x8*>(h0c + rdoff);
        f16x8 B1 = *reinterpret_cast<const f16x8*>(h0c + 64 + rdoff);
        f16x8 B2 = *reinterpret_cast<const f16x8*>(h1c + rdoff);
        f16x8 B3 = *reinterpret_cast<const f16x8*>(h1c + 64 + rdoff);
        f32x4 a0 = zf4, a1 = zf4;
        a0 = MFMAH(w16[0][0], B0, a0); a1 = MFMAH(w16[1][0], B0, a1);
        a0 = MFMAH(w16[0][1], B1, a0); a1 = MFMAH(w16[1][1], B1, a1);
        a0 = MFMAH(w16[0][2], B2, a0); a1 = MFMAH(w16[1][2], B2, a1);
        a0 = MFMAH(w16[0][3], B3, a0); a1 = MFMAH(w16[1][3], B3, a1);
        if (col < NCH) {
          *reinterpret_cast<f32x4*>(&zp[1][col][32 * w8 + 4 * lq])      = a0;
          *reinterpret_cast<f32x4*>(&zp[1][col][32 * w8 + 16 + 4 * lq]) = a1;
        }
      }
    }

    lds_barrier();
    if (L == 0) { xb0 = xbn0; xb1 = xbn1; }
  }
#undef GATES
#undef HSTORE

  // ---- FC epilogue: out = fc_w . h2[T-1] + fc_b ----
  if (tid < NCH) {
    float acc = fc_b[0];
#pragma unroll
    for (int h = 0; h < H; ++h) acc += fcw_s[h] * hfin[tid][h];
    out[blk * NCH + tid] = acc;
  }
}

extern "C" void kernel_launch(void* const* d_in, const int* in_sizes, int n_in,
                              void* d_out, int out_size, void* d_ws, size_t ws_size,
                              hipStream_t stream) {
  const float* x     = (const float*)d_in[0];
  const float* w_ih0 = (const float*)d_in[1];
  const float* w_hh0 = (const float*)d_in[2];
  const float* b_ih0 = (const float*)d_in[3];
  const float* b_hh0 = (const float*)d_in[4];
  const float* w_ih1 = (const float*)d_in[5];
  const float* w_hh1 = (const float*)d_in[6];
  const float* b_ih1 = (const float*)d_in[7];
  const float* b_hh1 = (const float*)d_in[8];
  const float* fc_w  = (const float*)d_in[9];
  const float* fc_b  = (const float*)d_in[10];
  float* out = (float*)d_out;

  _Float16* xfrag = (_Float16*)d_ws;  // 64 MiB used

  xconv<<<dim3(8192), dim3(256), 0, stream>>>(x, xfrag);
  lstm_fused<<<dim3(NBLK), dim3(NTHR), 0, stream>>>(
      xfrag, w_ih0, w_hh0, b_ih0, b_hh0, w_ih1, w_hh1, b_ih1, b_hh1,
      fc_w, fc_b, out);
}